// Round 5
// baseline (152.295 us; speedup 1.0000x reference)
//
#include <hip/hip_runtime.h>
#include <hip/hip_bf16.h>
#include <cstdint>
#include <cstddef>

// Problem dims (fixed by the reference)
#define NEXP   8
#define BATCH  8
#define NTOK   2048
#define DDIM   512
#define DFFDIM 2048
#define DCOND  512

typedef float  f32x4  __attribute__((ext_vector_type(4)));
typedef __bf16 bf16x8 __attribute__((ext_vector_type(8)));

using as1_cvoid = __attribute__((address_space(1))) const void;
using as3_void  = __attribute__((address_space(3))) void;

__device__ __forceinline__ void async_copy16(const void* g, void* l) {
  __builtin_amdgcn_global_load_lds((as1_cvoid*)g, (as3_void*)l, 16, 0, 0);
}

__device__ __forceinline__ unsigned short f2bf_bits(float f) {
  __hip_bfloat16 h = __float2bfloat16(f);
  return *reinterpret_cast<unsigned short*>(&h);
}

// fast tanh-approx gelu: 0.5v(1+tanh(z)) == v * sigmoid(2z)
__device__ __forceinline__ float gelu_fast(float v) {
  float y = v * fmaf(0.0713548162726f, v * v, 1.5957691216057f);
  float e = exp2f(-1.44269504089f * y);
  return v * __builtin_amdgcn_rcpf(1.0f + e);
}

// ---------------------------------------------------------------------------
// 1) scale/shift = cond[b] @ W_cond[route[b]] + b_cond[route[b]] -> ss[B][1024]
// ---------------------------------------------------------------------------
__global__ void mod_kernel(const float* __restrict__ cond,
                           const int* __restrict__ route,
                           const float* __restrict__ W_cond,
                           const float* __restrict__ b_cond,
                           float* __restrict__ ss) {
  const int b = blockIdx.y;
  const int m = route[b];
  const int tj = threadIdx.x & 63;
  const int cq = threadIdx.x >> 6;            // 0..3
  const int j = blockIdx.x * 64 + tj;
  const float* wc = W_cond + (size_t)m * DCOND * (2 * DDIM);
  const float* cb = cond + (size_t)b * DCOND;
  float acc = 0.f;
#pragma unroll 4
  for (int c = cq * 128; c < cq * 128 + 128; ++c)
    acc += cb[c] * wc[(size_t)c * (2 * DDIM) + j];
  __shared__ float red[4][64];
  red[cq][tj] = acc;
  __syncthreads();
  if (cq == 0) {
    float v = red[0][tj] + red[1][tj] + red[2][tj] + red[3][tj];
    ss[(size_t)b * (2 * DDIM) + j] = v + b_cond[(size_t)m * (2 * DDIM) + j];
  }
}

// ---------------------------------------------------------------------------
// 2) x_mod = bf16( x * (1+scale) + shift )   [B][N][D] bf16
// ---------------------------------------------------------------------------
__global__ void film_kernel(const float* __restrict__ x,
                            const float* __restrict__ ss,
                            __hip_bfloat16* __restrict__ xmod) {
  const size_t idx = (size_t)blockIdx.x * blockDim.x + threadIdx.x;
  const int d4 = (int)(idx & (DDIM / 4 - 1));
  const int b  = (int)(idx >> 18);
  const float4 xv = reinterpret_cast<const float4*>(x)[idx];
  const float4 sc = reinterpret_cast<const float4*>(ss + (size_t)b * 1024)[d4];
  const float4 sh = reinterpret_cast<const float4*>(ss + (size_t)b * 1024 + DDIM)[d4];
  float r0 = xv.x * (1.f + sc.x) + sh.x;
  float r1 = xv.y * (1.f + sc.y) + sh.y;
  float r2 = xv.z * (1.f + sc.z) + sh.z;
  float r3 = xv.w * (1.f + sc.w) + sh.w;
  ushort4 ov;
  ov.x = f2bf_bits(r0); ov.y = f2bf_bits(r1);
  ov.z = f2bf_bits(r2); ov.w = f2bf_bits(r3);
  reinterpret_cast<ushort4*>(xmod)[idx] = ov;
}

// ---------------------------------------------------------------------------
// 3) transpose + f32->bf16:  in [M][L][R] f32  ->  out [M][R][L] bf16
// ---------------------------------------------------------------------------
__global__ void transpose_cvt(const float* __restrict__ in,
                              __hip_bfloat16* __restrict__ outp,
                              int L, int R,
                              const int* __restrict__ route) {
  const int mi = blockIdx.z;
  bool used = false;
#pragma unroll
  for (int b = 0; b < BATCH; ++b) used |= (route[b] == mi);
  if (!used) return;

  __shared__ float tile[32][33];
  const float* inm = in + (size_t)mi * L * R;
  __hip_bfloat16* outm = outp + (size_t)mi * L * R;
  const int r0 = blockIdx.x * 32, l0 = blockIdx.y * 32;
  const int tx = threadIdx.x, ty = threadIdx.y;
#pragma unroll
  for (int i = 0; i < 32; i += 8)
    tile[ty + i][tx] = inm[(size_t)(l0 + ty + i) * R + r0 + tx];
  __syncthreads();
#pragma unroll
  for (int i = 0; i < 32; i += 8)
    outm[(size_t)(r0 + ty + i) * L + l0 + tx] = __float2bfloat16(tile[tx][ty + i]);
}

// ---------------------------------------------------------------------------
// 4) 3-slot pipelined GEMM: BM=256, BN=128, BK=64, 512 threads (8 waves 2Mx4N,
//    wave-tile 128x32).  T2 XOR-swizzle (linear gload_lds dest +
//    inverse-swizzled global src + swizzled ds_read).  Depth-2 prefetch,
//    counted vmcnt(6); ONE barrier + ONE waitcnt per K-tile; reads+MFMA left
//    to the compiler scheduler (no manual lgkm fences -> fine-grained
//    interleave, m97-style).  3 LDS slots make the staged slot one that was
//    last read 3 tiles ago, so no read-protection barrier is needed.
//    EPI=0: bf16(gelu(acc+bias));  EPI=1: f32(acc+bias).
// ---------------------------------------------------------------------------
template <int EPI>
__global__ __launch_bounds__(512, 1) void gemm_pipe3(
    const __hip_bfloat16* __restrict__ Abase,
    const __hip_bfloat16* __restrict__ Btbase,
    const float* __restrict__ biasbase,
    void* __restrict__ outbase,
    const int* __restrict__ route,
    int Mdim, int Ndim, int Kdim, int tilesX) {
  const int bid  = blockIdx.x;
  const int b    = bid & 7;            // batch -> XCD
  const int tile = bid >> 3;
  const int bx   = tile % tilesX;      // M-tile
  const int by   = tile / tilesX;      // N-tile
  const int m = route[b];
  const __hip_bfloat16* A  = Abase  + (size_t)b * Mdim * Kdim;
  const __hip_bfloat16* Bt = Btbase + (size_t)m * Ndim * Kdim;
  const float* bias = biasbase + (size_t)m * Ndim;
  const int r0 = bx * 256;
  const int n0 = by * 128;

  __shared__ alignas(16) __hip_bfloat16 As[3][256 * 64];   // 96 KB
  __shared__ alignas(16) __hip_bfloat16 Bs[3][128 * 64];   // 48 KB

  const int t = threadIdx.x;
  const int w = t >> 6, l = t & 63;
  const int wm = w >> 2, wn = w & 3;   // 2 x 4 waves

  // staging source (inverse-swizzled global chunk); LDS dest linear.
  // LDS(row r, chunk c) holds global(row r, chunk c ^ (r&7)).
  const int srow = t >> 3;                     // 0..63
  const int scol = (t & 7) ^ ((t >> 3) & 7);   // 16B chunk in row

#define STAGE(s_, k0)                                                         \
  { _Pragma("unroll")                                                         \
    for (int i = 0; i < 4; ++i)                                               \
      async_copy16(A + (size_t)(r0 + i * 64 + srow) * Kdim + (k0) + scol * 8, \
                   &As[s_][(i * 512 + w * 64) * 8]);                          \
    _Pragma("unroll")                                                         \
    for (int i = 0; i < 2; ++i)                                               \
      async_copy16(Bt + (size_t)(n0 + i * 64 + srow) * Kdim + (k0) + scol * 8,\
                   &Bs[s_][(i * 512 + w * 64) * 8]); }

  // ds_read addresses (swizzled)
  const int lrow = l & 15, lq = l >> 4, lx = l & 7;
  const int abase = (wm * 128 + lrow) * 8;     // 16B units
  const int bbase = (wn * 32 + lrow) * 8;
  const int swz0 = (lq) ^ lx;                  // kk=0 chunk
  const int swz1 = (4 + lq) ^ lx;              // kk=1 chunk

  f32x4 acc[8][2] = {};
  const int nt = Kdim >> 6;

  // prologue: stage tiles 0,1 into slots 0,1 (6 loads each, depth-2)
  STAGE(0, 0)
  STAGE(1, 64)

  int s = 0;
  for (int kt = 0; kt < nt; ++kt) {
    // own 6 loads for tile kt complete (newest 6 = tile kt+1's stay in flight)
    if (kt + 1 < nt) asm volatile("s_waitcnt vmcnt(6)" ::: "memory");
    else             asm volatile("s_waitcnt vmcnt(0)" ::: "memory");
    __builtin_amdgcn_s_barrier();          // everyone's tile-kt loads landed
    __builtin_amdgcn_sched_barrier(0);     // nothing below moves above barrier

    // stage kt+2 into slot s2 (last read at tile kt-1 -> protected by barrier)
    int s2 = s + 2; if (s2 >= 3) s2 -= 3;
    if (kt + 2 < nt) STAGE(s2, (kt + 2) * 64)

    // reads + MFMA: NO fences — compiler emits fine-grained lgkmcnt interleave
    const __hip_bfloat16* as_ = As[s];
    const __hip_bfloat16* bs_ = Bs[s];
    bf16x8 af[8][2], bfr[2][2];
#pragma unroll
    for (int nb = 0; nb < 2; ++nb) {
      bfr[nb][0] = *reinterpret_cast<const bf16x8*>(&bs_[(bbase + nb * 128 + swz0) * 8]);
      bfr[nb][1] = *reinterpret_cast<const bf16x8*>(&bs_[(bbase + nb * 128 + swz1) * 8]);
    }
#pragma unroll
    for (int mb = 0; mb < 8; ++mb) {
      af[mb][0] = *reinterpret_cast<const bf16x8*>(&as_[(abase + mb * 128 + swz0) * 8]);
      af[mb][1] = *reinterpret_cast<const bf16x8*>(&as_[(abase + mb * 128 + swz1) * 8]);
    }
#pragma unroll
    for (int mb = 0; mb < 8; ++mb)
#pragma unroll
      for (int nb = 0; nb < 2; ++nb) {
        acc[mb][nb] = __builtin_amdgcn_mfma_f32_16x16x32_bf16(
            af[mb][0], bfr[nb][0], acc[mb][nb], 0, 0, 0);
        acc[mb][nb] = __builtin_amdgcn_mfma_f32_16x16x32_bf16(
            af[mb][1], bfr[nb][1], acc[mb][nb], 0, 0, 0);
      }

    ++s; if (s == 3) s = 0;
  }
#undef STAGE

  // ---- epilogue: C/D layout col=lane&15, row=(lane>>4)*4+j ----
  if (EPI == 0) {
    __hip_bfloat16* out = (__hip_bfloat16*)outbase + (size_t)b * Mdim * Ndim;
#pragma unroll
    for (int mb = 0; mb < 8; ++mb) {
      const int row = r0 + wm * 128 + mb * 16 + lq * 4;
#pragma unroll
      for (int nb = 0; nb < 2; ++nb) {
        const int col = n0 + wn * 32 + nb * 16 + lrow;
        const float bv = bias[col];
#pragma unroll
        for (int j = 0; j < 4; ++j) {
          float g = gelu_fast(acc[mb][nb][j] + bv);
          out[(size_t)(row + j) * Ndim + col] = __float2bfloat16(g);
        }
      }
    }
  } else {
    float* out = (float*)outbase + (size_t)b * Mdim * Ndim;
#pragma unroll
    for (int mb = 0; mb < 8; ++mb) {
      const int row = r0 + wm * 128 + mb * 16 + lq * 4;
#pragma unroll
      for (int nb = 0; nb < 2; ++nb) {
        const int col = n0 + wn * 32 + nb * 16 + lrow;
        const float bv = bias[col];
#pragma unroll
        for (int j = 0; j < 4; ++j)
          out[(size_t)(row + j) * Ndim + col] = acc[mb][nb][j] + bv;
      }
    }
  }
}

// ---------------------------------------------------------------------------
extern "C" void kernel_launch(void* const* d_in, const int* in_sizes, int n_in,
                              void* d_out, int out_size, void* d_ws, size_t ws_size,
                              hipStream_t stream) {
  const float* x      = (const float*)d_in[0];
  const float* cond   = (const float*)d_in[1];
  const int*   route  = (const int*)d_in[2];
  const float* W_cond = (const float*)d_in[3];
  const float* b_cond = (const float*)d_in[4];
  const float* W1     = (const float*)d_in[5];
  const float* b1     = (const float*)d_in[6];
  const float* W2     = (const float*)d_in[7];
  const float* b2     = (const float*)d_in[8];
  float* out = (float*)d_out;

  // workspace layout (bytes)
  const size_t SS_OFF   = 0;
  const size_t XMOD_OFF = 32768;
  const size_t W1T_OFF  = XMOD_OFF + (size_t)BATCH * NTOK * DDIM * 2;
  const size_t W2T_OFF  = W1T_OFF + (size_t)NEXP * DDIM * DFFDIM * 2;
  const size_t H_OFF    = W2T_OFF + (size_t)NEXP * DFFDIM * DDIM * 2;
  const size_t NEED     = H_OFF + (size_t)BATCH * NTOK * DFFDIM * 2;
  if (ws_size < NEED) return;

  char* ws = (char*)d_ws;
  float* ss            = (float*)(ws + SS_OFF);
  __hip_bfloat16* xmod = (__hip_bfloat16*)(ws + XMOD_OFF);
  __hip_bfloat16* w1t  = (__hip_bfloat16*)(ws + W1T_OFF);
  __hip_bfloat16* w2t  = (__hip_bfloat16*)(ws + W2T_OFF);
  __hip_bfloat16* h    = (__hip_bfloat16*)(ws + H_OFF);

  // 1) cond modulation
  mod_kernel<<<dim3(2 * DDIM / 64, BATCH), 256, 0, stream>>>(cond, route, W_cond, b_cond, ss);

  // 2) FiLM -> bf16
  {
    const size_t groups = (size_t)BATCH * NTOK * DDIM / 4;
    film_kernel<<<(unsigned)(groups / 256), 256, 0, stream>>>(x, ss, xmod);
  }

  // 3) weight transpose+convert (routed experts only)
  transpose_cvt<<<dim3(DFFDIM / 32, DDIM / 32, NEXP), dim3(32, 8), 0, stream>>>(W1, w1t, DDIM, DFFDIM, route);
  transpose_cvt<<<dim3(DDIM / 32, DFFDIM / 32, NEXP), dim3(32, 8), 0, stream>>>(W2, w2t, DFFDIM, DDIM, route);

  // 4) GEMM1: h = gelu(xmod @ W1 + b1)   grid 8*16*8 = 1024 blocks
  gemm_pipe3<0><<<(NTOK / 256) * (DFFDIM / 128) * BATCH, 512, 0, stream>>>(
      xmod, w1t, b1, h, route, NTOK, DFFDIM, DDIM, NTOK / 256);

  // 5) GEMM2: out = h @ W2 + b2          grid 8*4*8 = 256 blocks
  gemm_pipe3<1><<<(NTOK / 256) * (DDIM / 128) * BATCH, 512, 0, stream>>>(
      h, w2t, b2, out, route, NTOK, DDIM, DFFDIM, NTOK / 256);
}

// Round 6
// 137.203 us; speedup vs baseline: 1.1100x; 1.1100x over previous
//
#include <hip/hip_runtime.h>
#include <hip/hip_bf16.h>
#include <cstdint>
#include <cstddef>

// Problem dims (fixed by the reference)
#define NEXP   8
#define BATCH  8
#define NTOK   2048
#define DDIM   512
#define DFFDIM 2048
#define DCOND  512

typedef float  f32x4  __attribute__((ext_vector_type(4)));
typedef __bf16 bf16x8 __attribute__((ext_vector_type(8)));

using as1_cvoid = __attribute__((address_space(1))) const void;
using as3_void  = __attribute__((address_space(3))) void;

__device__ __forceinline__ void async_copy16(const void* g, void* l) {
  __builtin_amdgcn_global_load_lds((as1_cvoid*)g, (as3_void*)l, 16, 0, 0);
}

__device__ __forceinline__ unsigned short f2bf_bits(float f) {
  __hip_bfloat16 h = __float2bfloat16(f);
  return *reinterpret_cast<unsigned short*>(&h);
}

// fast tanh-approx gelu: 0.5v(1+tanh(z)) == v * sigmoid(2z)
__device__ __forceinline__ float gelu_fast(float v) {
  float y = v * fmaf(0.0713548162726f, v * v, 1.5957691216057f);
  float e = exp2f(-1.44269504089f * y);
  return v * __builtin_amdgcn_rcpf(1.0f + e);
}

// ---------------------------------------------------------------------------
// 1) scale/shift = cond[b] @ W_cond[route[b]] + b_cond[route[b]] -> ss[B][1024]
// ---------------------------------------------------------------------------
__global__ void mod_kernel(const float* __restrict__ cond,
                           const int* __restrict__ route,
                           const float* __restrict__ W_cond,
                           const float* __restrict__ b_cond,
                           float* __restrict__ ss) {
  const int b = blockIdx.y;
  const int m = route[b];
  const int tj = threadIdx.x & 63;
  const int cq = threadIdx.x >> 6;            // 0..3
  const int j = blockIdx.x * 64 + tj;
  const float* wc = W_cond + (size_t)m * DCOND * (2 * DDIM);
  const float* cb = cond + (size_t)b * DCOND;
  float acc = 0.f;
#pragma unroll 4
  for (int c = cq * 128; c < cq * 128 + 128; ++c)
    acc += cb[c] * wc[(size_t)c * (2 * DDIM) + j];
  __shared__ float red[4][64];
  red[cq][tj] = acc;
  __syncthreads();
  if (cq == 0) {
    float v = red[0][tj] + red[1][tj] + red[2][tj] + red[3][tj];
    ss[(size_t)b * (2 * DDIM) + j] = v + b_cond[(size_t)m * (2 * DDIM) + j];
  }
}

// ---------------------------------------------------------------------------
// 2) x_mod = bf16( x * (1+scale) + shift )   [B][N][D] bf16
// ---------------------------------------------------------------------------
__global__ void film_kernel(const float* __restrict__ x,
                            const float* __restrict__ ss,
                            __hip_bfloat16* __restrict__ xmod) {
  const size_t idx = (size_t)blockIdx.x * blockDim.x + threadIdx.x;
  const int d4 = (int)(idx & (DDIM / 4 - 1));
  const int b  = (int)(idx >> 18);
  const float4 xv = reinterpret_cast<const float4*>(x)[idx];
  const float4 sc = reinterpret_cast<const float4*>(ss + (size_t)b * 1024)[d4];
  const float4 sh = reinterpret_cast<const float4*>(ss + (size_t)b * 1024 + DDIM)[d4];
  float r0 = xv.x * (1.f + sc.x) + sh.x;
  float r1 = xv.y * (1.f + sc.y) + sh.y;
  float r2 = xv.z * (1.f + sc.z) + sh.z;
  float r3 = xv.w * (1.f + sc.w) + sh.w;
  ushort4 ov;
  ov.x = f2bf_bits(r0); ov.y = f2bf_bits(r1);
  ov.z = f2bf_bits(r2); ov.w = f2bf_bits(r3);
  reinterpret_cast<ushort4*>(xmod)[idx] = ov;
}

// ---------------------------------------------------------------------------
// 3) transpose + f32->bf16:  in [M][L][R] f32  ->  out [M][R][L] bf16
// ---------------------------------------------------------------------------
__global__ void transpose_cvt(const float* __restrict__ in,
                              __hip_bfloat16* __restrict__ outp,
                              int L, int R,
                              const int* __restrict__ route) {
  const int mi = blockIdx.z;
  bool used = false;
#pragma unroll
  for (int b = 0; b < BATCH; ++b) used |= (route[b] == mi);
  if (!used) return;

  __shared__ float tile[32][33];
  const float* inm = in + (size_t)mi * L * R;
  __hip_bfloat16* outm = outp + (size_t)mi * L * R;
  const int r0 = blockIdx.x * 32, l0 = blockIdx.y * 32;
  const int tx = threadIdx.x, ty = threadIdx.y;
#pragma unroll
  for (int i = 0; i < 32; i += 8)
    tile[ty + i][tx] = inm[(size_t)(l0 + ty + i) * R + r0 + tx];
  __syncthreads();
#pragma unroll
  for (int i = 0; i < 32; i += 8)
    outm[(size_t)(r0 + ty + i) * L + l0 + tx] = __float2bfloat16(tile[tx][ty + i]);
}

// ---------------------------------------------------------------------------
// 4) GEMM: BM=BN=128, BK=64, 256 threads (4 waves 2x2, wave-tile 64x64).
//    2-slot LDS double-buffer (64 KB -> 2 blocks/CU: cross-block overlap of
//    barrier/vmcnt stalls, m114 mechanism).  T2 XOR-swizzle (linear
//    global_load_lds dest + inverse-swizzled global src + swizzled ds_read;
//    measured conflicts 1.26e7 -> 0).  Depth-1 prefetch, counted vmcnt(8):
//    stage tile kt+1 at iteration top, wait only for tile kt's loads (issued
//    one full compute-phase earlier).  Two raw s_barriers per tile, no lgkm
//    fences — compiler emits fine-grained lgkmcnt interleave (m97-style).
//      entry barrier : all waves' tile-kt loads landed in slot s
//      trail barrier : all waves' reads of slot s done (MFMA data-dependence
//                      forces ds_read completion before the last MFMA issue)
//                      -> next iteration may overwrite slot s
//    EPI=0: bf16(gelu(acc+bias));  EPI=1: f32(acc+bias).
// ---------------------------------------------------------------------------
template <int EPI>
__global__ __launch_bounds__(256, 2) void gemm_db2(
    const __hip_bfloat16* __restrict__ Abase,
    const __hip_bfloat16* __restrict__ Btbase,
    const float* __restrict__ biasbase,
    void* __restrict__ outbase,
    const int* __restrict__ route,
    int Mdim, int Ndim, int Kdim, int tilesX) {
  const int bid  = blockIdx.x;
  const int b    = bid & 7;            // batch -> XCD
  const int tile = bid >> 3;
  const int bx   = tile % tilesX;      // M-tile
  const int by   = tile / tilesX;      // N-tile
  const int m = route[b];
  const __hip_bfloat16* A  = Abase  + (size_t)b * Mdim * Kdim;
  const __hip_bfloat16* Bt = Btbase + (size_t)m * Ndim * Kdim;
  const float* bias = biasbase + (size_t)m * Ndim;
  const int r0 = bx * 128;
  const int n0 = by * 128;

  __shared__ alignas(16) __hip_bfloat16 As[2][128 * 64];   // 32 KB
  __shared__ alignas(16) __hip_bfloat16 Bs[2][128 * 64];   // 32 KB

  const int t = threadIdx.x;
  const int w = t >> 6, l = t & 63;
  const int wr = w >> 1, wc = w & 1;   // 2 x 2 waves, wave-tile 64x64

  // staging: chunk c_lin = i*256 + t  ->  LDS row i*32 + (t>>3), chunk t&7.
  // LDS(row r, chunk c) holds global(row r, chunk c ^ (r&7)); dest linear.
  const int srow = t >> 3;                     // 0..31 within 32-row group
  const int scol = (t & 7) ^ ((t >> 3) & 7);   // inverse-swizzled 16B chunk

#define STAGE(s_, k0)                                                         \
  { _Pragma("unroll")                                                         \
    for (int i = 0; i < 4; ++i)                                               \
      async_copy16(A + (size_t)(r0 + i * 32 + srow) * Kdim + (k0) + scol * 8, \
                   &As[s_][(i * 256 + t) * 8]);                               \
    _Pragma("unroll")                                                         \
    for (int i = 0; i < 4; ++i)                                               \
      async_copy16(Bt + (size_t)(n0 + i * 32 + srow) * Kdim + (k0) + scol * 8,\
                   &Bs[s_][(i * 256 + t) * 8]); }

  // ds_read addresses (swizzled): row&7 == l&7 for every fragment row
  const int lrow = l & 15, lq = l >> 4, lx = l & 7;
  f32x4 acc[4][4] = {};
  const int nt = Kdim >> 6;

  STAGE(0, 0)                                  // prologue: tile 0 -> slot 0

  for (int kt = 0; kt < nt; ++kt) {
    const int s = kt & 1;
    if (kt + 1 < nt) {
      STAGE(s ^ 1, (kt + 1) * 64)              // prefetch next tile
      asm volatile("s_waitcnt vmcnt(8)" ::: "memory");  // tile kt's 8 done
    } else {
      asm volatile("s_waitcnt vmcnt(0)" ::: "memory");
    }
    __builtin_amdgcn_s_barrier();              // slot s complete block-wide
    __builtin_amdgcn_sched_barrier(0);

    // reads + MFMA: no fences — compiler interleaves with lgkmcnt(N)
    const __hip_bfloat16* as_ = As[s];
    const __hip_bfloat16* bs_ = Bs[s];
    bf16x8 af[4][2], bfr[4][2];
#pragma unroll
    for (int mb = 0; mb < 4; ++mb) {
      const int row = wr * 64 + mb * 16 + lrow;
      af[mb][0] = *reinterpret_cast<const bf16x8*>(&as_[(row * 8 + ((0 + lq) ^ lx)) * 8]);
      af[mb][1] = *reinterpret_cast<const bf16x8*>(&as_[(row * 8 + ((4 + lq) ^ lx)) * 8]);
    }
#pragma unroll
    for (int nb = 0; nb < 4; ++nb) {
      const int row = wc * 64 + nb * 16 + lrow;
      bfr[nb][0] = *reinterpret_cast<const bf16x8*>(&bs_[(row * 8 + ((0 + lq) ^ lx)) * 8]);
      bfr[nb][1] = *reinterpret_cast<const bf16x8*>(&bs_[(row * 8 + ((4 + lq) ^ lx)) * 8]);
    }
#pragma unroll
    for (int mb = 0; mb < 4; ++mb)
#pragma unroll
      for (int nb = 0; nb < 4; ++nb) {
        acc[mb][nb] = __builtin_amdgcn_mfma_f32_16x16x32_bf16(
            af[mb][0], bfr[nb][0], acc[mb][nb], 0, 0, 0);
        acc[mb][nb] = __builtin_amdgcn_mfma_f32_16x16x32_bf16(
            af[mb][1], bfr[nb][1], acc[mb][nb], 0, 0, 0);
      }

    __builtin_amdgcn_sched_barrier(0);
    __builtin_amdgcn_s_barrier();              // reads of slot s done
  }
#undef STAGE

  // ---- epilogue: C/D layout col=lane&15, row=(lane>>4)*4+j ----
  if (EPI == 0) {
    __hip_bfloat16* out = (__hip_bfloat16*)outbase + (size_t)b * Mdim * Ndim;
#pragma unroll
    for (int mb = 0; mb < 4; ++mb) {
      const int row = r0 + wr * 64 + mb * 16 + lq * 4;
#pragma unroll
      for (int nb = 0; nb < 4; ++nb) {
        const int col = n0 + wc * 64 + nb * 16 + lrow;
        const float bv = bias[col];
#pragma unroll
        for (int j = 0; j < 4; ++j) {
          float g = gelu_fast(acc[mb][nb][j] + bv);
          out[(size_t)(row + j) * Ndim + col] = __float2bfloat16(g);
        }
      }
    }
  } else {
    float* out = (float*)outbase + (size_t)b * Mdim * Ndim;
#pragma unroll
    for (int mb = 0; mb < 4; ++mb) {
      const int row = r0 + wr * 64 + mb * 16 + lq * 4;
#pragma unroll
      for (int nb = 0; nb < 4; ++nb) {
        const int col = n0 + wc * 64 + nb * 16 + lrow;
        const float bv = bias[col];
#pragma unroll
        for (int j = 0; j < 4; ++j)
          out[(size_t)(row + j) * Ndim + col] = acc[mb][nb][j] + bv;
      }
    }
  }
}

// ---------------------------------------------------------------------------
extern "C" void kernel_launch(void* const* d_in, const int* in_sizes, int n_in,
                              void* d_out, int out_size, void* d_ws, size_t ws_size,
                              hipStream_t stream) {
  const float* x      = (const float*)d_in[0];
  const float* cond   = (const float*)d_in[1];
  const int*   route  = (const int*)d_in[2];
  const float* W_cond = (const float*)d_in[3];
  const float* b_cond = (const float*)d_in[4];
  const float* W1     = (const float*)d_in[5];
  const float* b1     = (const float*)d_in[6];
  const float* W2     = (const float*)d_in[7];
  const float* b2     = (const float*)d_in[8];
  float* out = (float*)d_out;

  // workspace layout (bytes)
  const size_t SS_OFF   = 0;
  const size_t XMOD_OFF = 32768;
  const size_t W1T_OFF  = XMOD_OFF + (size_t)BATCH * NTOK * DDIM * 2;
  const size_t W2T_OFF  = W1T_OFF + (size_t)NEXP * DDIM * DFFDIM * 2;
  const size_t H_OFF    = W2T_OFF + (size_t)NEXP * DFFDIM * DDIM * 2;
  const size_t NEED     = H_OFF + (size_t)BATCH * NTOK * DFFDIM * 2;
  if (ws_size < NEED) return;

  char* ws = (char*)d_ws;
  float* ss            = (float*)(ws + SS_OFF);
  __hip_bfloat16* xmod = (__hip_bfloat16*)(ws + XMOD_OFF);
  __hip_bfloat16* w1t  = (__hip_bfloat16*)(ws + W1T_OFF);
  __hip_bfloat16* w2t  = (__hip_bfloat16*)(ws + W2T_OFF);
  __hip_bfloat16* h    = (__hip_bfloat16*)(ws + H_OFF);

  // 1) cond modulation
  mod_kernel<<<dim3(2 * DDIM / 64, BATCH), 256, 0, stream>>>(cond, route, W_cond, b_cond, ss);

  // 2) FiLM -> bf16
  {
    const size_t groups = (size_t)BATCH * NTOK * DDIM / 4;
    film_kernel<<<(unsigned)(groups / 256), 256, 0, stream>>>(x, ss, xmod);
  }

  // 3) weight transpose+convert (routed experts only)
  transpose_cvt<<<dim3(DFFDIM / 32, DDIM / 32, NEXP), dim3(32, 8), 0, stream>>>(W1, w1t, DDIM, DFFDIM, route);
  transpose_cvt<<<dim3(DDIM / 32, DFFDIM / 32, NEXP), dim3(32, 8), 0, stream>>>(W2, w2t, DFFDIM, DDIM, route);

  // 4) GEMM1: h = gelu(xmod @ W1 + b1)   grid 16*16*8 = 2048 blocks
  gemm_db2<0><<<(NTOK / 128) * (DFFDIM / 128) * BATCH, 256, 0, stream>>>(
      xmod, w1t, b1, h, route, NTOK, DFFDIM, DDIM, NTOK / 128);

  // 5) GEMM2: out = h @ W2 + b2          grid 16*4*8 = 512 blocks
  gemm_db2<1><<<(NTOK / 128) * (DDIM / 128) * BATCH, 256, 0, stream>>>(
      h, w2t, b2, out, route, NTOK, DDIM, DFFDIM, NTOK / 128);
}